// Round 6
// baseline (165.588 us; speedup 1.0000x reference)
//
#include <hip/hip_runtime.h>
#include <stdint.h>

#define NXS 8192
#define HS  1024

typedef __attribute__((ext_vector_type(8))) short short8;
typedef __attribute__((ext_vector_type(4))) float f32x4;

__device__ __forceinline__ float bf2f(uint32_t b) {
    union { uint32_t u; float f; } c; c.u = b << 16; return c.f;
}
__device__ __forceinline__ uint16_t f2bf(float f) {
    union { float f; uint32_t u; } c; c.f = f;
    return (uint16_t)((c.u + 0x7fffu + ((c.u >> 16) & 1u)) >> 16);
}
__device__ __forceinline__ void async_cp16(const void* g, void* l) {
    __builtin_amdgcn_global_load_lds(
        (const __attribute__((address_space(1))) void*)g,
        (__attribute__((address_space(3))) void*)l,
        16, 0, 0);
}

// ---- K0: W2 fp32 -> W2c (bf16 row-major) + W2T (bf16 transposed);
//      also zero yacc (8192 f32) and dacc (65536 f32) ----
__global__ __launch_bounds__(256) void conv_w2(
    const float* __restrict__ W2, uint16_t* __restrict__ W2c,
    uint16_t* __restrict__ W2T, float* __restrict__ yacc,
    float* __restrict__ dacc)
{
    __shared__ uint16_t tile[64][65];
    const int gid = blockIdx.x * 256 + threadIdx.x;   // 0..65535
    dacc[gid] = 0.f;
    if (gid < NXS) yacc[gid] = 0.f;
    const int bx = blockIdx.x & 15, by = blockIdx.x >> 4;
    const int tx = threadIdx.x & 63, ty = threadIdx.x >> 6;
#pragma unroll
    for (int rr = 0; rr < 64; rr += 4) {
        int r = ty + rr;
        uint16_t v = f2bf(W2[(size_t)(by * 64 + r) * HS + bx * 64 + tx]);
        W2c[(size_t)(by * 64 + r) * HS + bx * 64 + tx] = v;
        tile[r][tx] = v;
    }
    __syncthreads();
#pragma unroll
    for (int rr = 0; rr < 64; rr += 4)
        W2T[(size_t)(bx * 64 + ty + rr) * HS + by * 64 + tx] = tile[tx][ty + rr];
}

// ---- K1: Z1 = tanh(x @ W1^T + b1); one block per sample n, 4 j per thread ----
__global__ __launch_bounds__(256) void k1_z1(
    const float* __restrict__ x, const float* __restrict__ W1,
    const float* __restrict__ b1, uint16_t* __restrict__ Z1)
{
    const int n = blockIdx.x;
    const int j = threadIdx.x * 4;
    float4 x0 = *(const float4*)(x + n * 8);
    float4 x1 = *(const float4*)(x + n * 8 + 4);
    float4 bb = *(const float4*)(b1 + j);
    float sv[4] = {bb.x, bb.y, bb.z, bb.w};
    ushort4 o;
    uint16_t* op = (uint16_t*)&o;
#pragma unroll
    for (int c = 0; c < 4; ++c) {
        float4 w0 = *(const float4*)(W1 + (j + c) * 8);
        float4 w1 = *(const float4*)(W1 + (j + c) * 8 + 4);
        float s = sv[c]
            + x0.x * w0.x + x0.y * w0.y + x0.z * w0.z + x0.w * w0.w
            + x1.x * w1.x + x1.y * w1.y + x1.z * w1.z + x1.w * w1.w;
        op[c] = f2bf(tanhf(s));
    }
    *(ushort4*)(Z1 + (size_t)n * HS + j) = o;
}

// -------- GEMM: 128x128 tile, 8 waves (512 thr), BK=64, swizzled LDS --------
// MODE 0: C = A @ B^T; epilogue tanh -> V (bf16), y atomics
// MODE 1: C = U = V @ W2 (B=W2T); FUSED deriv epilogue:
//         c = U*(1-z1^2), dacc[k][row] += sum_cols c*W1[col][k]  (no U store)
template <int MODE>
__global__ __launch_bounds__(512) void gemm_k(
    const uint16_t* __restrict__ A, const uint16_t* __restrict__ B,
    const float* __restrict__ bias, const float* __restrict__ W3,
    uint16_t* __restrict__ Out, float* __restrict__ yacc,
    const uint16_t* __restrict__ Z1, const float* __restrict__ W1,
    float* __restrict__ dacc)
{
    __shared__ __attribute__((aligned(16))) uint16_t lsA[2][128 * 64];
    __shared__ __attribute__((aligned(16))) uint16_t lsB[2][128 * 64];
    const int t = threadIdx.x;
    const int wave = t >> 6, lane = t & 63;
    const int lq = lane >> 4, lr = lane & 15;
    const int wm = wave >> 1, wn = wave & 1;         // wm 0..3, wn 0..1
    const int rowBase = blockIdx.x * 128;
    const int colBase = blockIdx.y * 128;

    const int s0 = t, s1 = 512 + t;
    const int r0 = s0 >> 3, q0 = (s0 & 7) ^ (r0 & 7);
    const int r1 = s1 >> 3, q1 = (s1 & 7) ^ (r1 & 7);
    const uint16_t* gA0 = A + (size_t)(rowBase + r0) * HS + q0 * 8;
    const uint16_t* gA1 = A + (size_t)(rowBase + r1) * HS + q1 * 8;
    const uint16_t* gB0 = B + (size_t)(colBase + r0) * HS + q0 * 8;
    const uint16_t* gB1 = B + (size_t)(colBase + r1) * HS + q1 * 8;

    f32x4 acc[2][4] = {};

    async_cp16(gA0, (char*)lsA[0] + s0 * 16);
    async_cp16(gA1, (char*)lsA[0] + s1 * 16);
    async_cp16(gB0, (char*)lsB[0] + s0 * 16);
    async_cp16(gB1, (char*)lsB[0] + s1 * 16);
    __syncthreads();

    int buf = 0;
    for (int k0 = 0; k0 < HS; k0 += 64, buf ^= 1) {
        if (k0 + 64 < HS) {
            const int ko = k0 + 64;
            async_cp16(gA0 + ko, (char*)lsA[buf ^ 1] + s0 * 16);
            async_cp16(gA1 + ko, (char*)lsA[buf ^ 1] + s1 * 16);
            async_cp16(gB0 + ko, (char*)lsB[buf ^ 1] + s0 * 16);
            async_cp16(gB1 + ko, (char*)lsB[buf ^ 1] + s1 * 16);
        }
#pragma unroll
        for (int kk = 0; kk < 64; kk += 32) {
            const int kq = (kk >> 3) + lq;
            short8 af[2], bfr[4];
#pragma unroll
            for (int ti = 0; ti < 2; ++ti) {
                int ar = wm * 32 + ti * 16 + lr;
                af[ti] = *(const short8*)((const short*)lsA[buf]
                          + ar * 64 + ((kq ^ (ar & 7)) << 3));
            }
#pragma unroll
            for (int tj = 0; tj < 4; ++tj) {
                int br = wn * 64 + tj * 16 + lr;
                bfr[tj] = *(const short8*)((const short*)lsB[buf]
                          + br * 64 + ((kq ^ (br & 7)) << 3));
            }
#pragma unroll
            for (int ti = 0; ti < 2; ++ti)
#pragma unroll
                for (int tj = 0; tj < 4; ++tj)
                    acc[ti][tj] = __builtin_amdgcn_mfma_f32_16x16x32_bf16(
                        af[ti], bfr[tj], acc[ti][tj], 0, 0, 0);
        }
        __syncthreads();
    }

    int cCol[4];
#pragma unroll
    for (int tj = 0; tj < 4; ++tj)
        cCol[tj] = colBase + wn * 64 + tj * 16 + lr;

    if (MODE == 0) {
        float cB[4], cW[4];
#pragma unroll
        for (int tj = 0; tj < 4; ++tj) { cB[tj] = bias[cCol[tj]]; cW[tj] = W3[cCol[tj]]; }
#pragma unroll
        for (int ti = 0; ti < 2; ++ti) {
#pragma unroll
            for (int r = 0; r < 4; ++r) {
                int row = rowBase + wm * 32 + ti * 16 + lq * 4 + r;
                float ys = 0.f;
#pragma unroll
                for (int tj = 0; tj < 4; ++tj) {
                    float z2 = tanhf(acc[ti][tj][r] + cB[tj]);
                    ys += z2 * cW[tj];
                    Out[(size_t)row * HS + cCol[tj]] = f2bf((1.f - z2 * z2) * cW[tj]);
                }
                ys += __shfl_xor(ys, 1); ys += __shfl_xor(ys, 2);
                ys += __shfl_xor(ys, 4); ys += __shfl_xor(ys, 8);
                if (lr == 0) atomicAdd(&yacc[row], ys);
            }
        }
    } else {
        // fused dydx epilogue: acc[ti][tj][r] = U[row][col]
#pragma unroll
        for (int ti = 0; ti < 2; ++ti) {
#pragma unroll
            for (int r = 0; r < 4; ++r) {
                int row = rowBase + wm * 32 + ti * 16 + lq * 4 + r;
                float pk[8] = {};
#pragma unroll
                for (int tj = 0; tj < 4; ++tj) {
                    float z1 = bf2f(Z1[(size_t)row * HS + cCol[tj]]);
                    float c = acc[ti][tj][r] * (1.f - z1 * z1);
                    float4 w0 = *(const float4*)(W1 + cCol[tj] * 8);
                    float4 w1 = *(const float4*)(W1 + cCol[tj] * 8 + 4);
                    pk[0] += c * w0.x; pk[1] += c * w0.y;
                    pk[2] += c * w0.z; pk[3] += c * w0.w;
                    pk[4] += c * w1.x; pk[5] += c * w1.y;
                    pk[6] += c * w1.z; pk[7] += c * w1.w;
                }
#pragma unroll
                for (int m = 1; m < 16; m <<= 1)
#pragma unroll
                    for (int k = 0; k < 8; ++k) pk[k] += __shfl_xor(pk[k], m);
                if (lr == 0) {
#pragma unroll
                    for (int k = 0; k < 8; ++k)
                        atomicAdd(&dacc[k * NXS + row], pk[k]);
                }
            }
        }
    }
}

// ---- K5: final assembly: y = yacc + b3; dydx = dacc (flat copy) ----
__global__ __launch_bounds__(256) void k5_out(
    const float* __restrict__ yacc, const float* __restrict__ dacc,
    const float* __restrict__ b3, float* __restrict__ out)
{
    const int idx = blockIdx.x * 256 + threadIdx.x;   // 0..73727
    if (idx < NXS) out[idx] = yacc[idx] + b3[0];
    else           out[idx] = dacc[idx - NXS];
}

extern "C" void kernel_launch(void* const* d_in, const int* in_sizes, int n_in,
                              void* d_out, int out_size, void* d_ws, size_t ws_size,
                              hipStream_t stream) {
    (void)in_sizes; (void)n_in; (void)out_size; (void)ws_size;
    const float* x  = (const float*)d_in[0];
    const float* W1 = (const float*)d_in[1];
    const float* b1 = (const float*)d_in[2];
    const float* W2 = (const float*)d_in[3];
    const float* b2 = (const float*)d_in[4];
    const float* W3 = (const float*)d_in[5];
    const float* b3 = (const float*)d_in[6];
    float* out = (float*)d_out;

    char* ws = (char*)d_ws;
    // ws layout:
    //   [0, 16MB)        Z1 bf16 (live through GEMM2's fused epilogue)
    //   [16MB, 32MB)     V bf16
    //   [32MB, 34MB)     W2c bf16 row-major
    //   [34MB, 36MB)     W2T bf16 transposed
    //   [36MB, +32KB)    yacc fp32
    //   [+32KB, +288KB)  dacc fp32 [8][8192]
    uint16_t* Z1  = (uint16_t*)(ws);
    uint16_t* V   = (uint16_t*)(ws + (size_t)16 * 1024 * 1024);
    uint16_t* W2c = (uint16_t*)(ws + (size_t)32 * 1024 * 1024);
    uint16_t* W2T = (uint16_t*)(ws + (size_t)34 * 1024 * 1024);
    float*    yac = (float*)   (ws + (size_t)36 * 1024 * 1024);
    float*    dac = (float*)   (ws + (size_t)36 * 1024 * 1024 + 32768);

    conv_w2<<<256, 256, 0, stream>>>(W2, W2c, W2T, yac, dac);
    k1_z1<<<NXS, 256, 0, stream>>>(x, W1, b1, Z1);
    gemm_k<0><<<dim3(NXS / 128, HS / 128), 512, 0, stream>>>(
        Z1, W2c, b2, W3, V, yac, nullptr, nullptr, nullptr);
    gemm_k<1><<<dim3(NXS / 128, HS / 128), 512, 0, stream>>>(
        V, W2T, nullptr, nullptr, nullptr, nullptr, Z1, W1, dac);
    k5_out<<<(NXS * 9 + 255) / 256, 256, 0, stream>>>(yac, dac, b3, out);
}

// Round 7
// 151.589 us; speedup vs baseline: 1.0924x; 1.0924x over previous
//
#include <hip/hip_runtime.h>
#include <stdint.h>

#define NXS 8192
#define HS  1024

typedef __attribute__((ext_vector_type(8))) short short8;
typedef __attribute__((ext_vector_type(4))) float f32x4;

__device__ __forceinline__ float bf2f(uint32_t b) {
    union { uint32_t u; float f; } c; c.u = b << 16; return c.f;
}
__device__ __forceinline__ uint16_t f2bf(float f) {
    union { float f; uint32_t u; } c; c.f = f;
    return (uint16_t)((c.u + 0x7fffu + ((c.u >> 16) & 1u)) >> 16);
}
__device__ __forceinline__ void async_cp16(const void* g, void* l) {
    __builtin_amdgcn_global_load_lds(
        (const __attribute__((address_space(1))) void*)g,
        (__attribute__((address_space(3))) void*)l,
        16, 0, 0);
}

// ---- K01: merged prep. blocks [0,8192): Z1=tanh(x@W1^T+b1);
//      [8192,8448): W2->W2c+W2T; [8448,8736): init out (y=b3, dydx=0) ----
__global__ __launch_bounds__(256) void k01(
    const float* __restrict__ x, const float* __restrict__ W1,
    const float* __restrict__ b1, const float* __restrict__ W2,
    const float* __restrict__ b3, uint16_t* __restrict__ Z1,
    uint16_t* __restrict__ W2c, uint16_t* __restrict__ W2T,
    float* __restrict__ out)
{
    __shared__ uint16_t tile[64][65];
    const int b = blockIdx.x;
    if (b < 8192) {
        const int n = b;
        const int j = threadIdx.x * 4;
        float4 x0 = *(const float4*)(x + n * 8);
        float4 x1 = *(const float4*)(x + n * 8 + 4);
        float4 bb = *(const float4*)(b1 + j);
        float sv[4] = {bb.x, bb.y, bb.z, bb.w};
        ushort4 o;
        uint16_t* op = (uint16_t*)&o;
#pragma unroll
        for (int c = 0; c < 4; ++c) {
            float4 w0 = *(const float4*)(W1 + (j + c) * 8);
            float4 w1 = *(const float4*)(W1 + (j + c) * 8 + 4);
            float s = sv[c]
                + x0.x * w0.x + x0.y * w0.y + x0.z * w0.z + x0.w * w0.w
                + x1.x * w1.x + x1.y * w1.y + x1.z * w1.z + x1.w * w1.w;
            op[c] = f2bf(tanhf(s));
        }
        *(ushort4*)(Z1 + (size_t)n * HS + j) = o;
    } else if (b < 8448) {
        const int bb2 = b - 8192;
        const int bx = bb2 & 15, by = bb2 >> 4;
        const int tx = threadIdx.x & 63, ty = threadIdx.x >> 6;
#pragma unroll
        for (int rr = 0; rr < 64; rr += 4) {
            int r = ty + rr;
            uint16_t v = f2bf(W2[(size_t)(by * 64 + r) * HS + bx * 64 + tx]);
            W2c[(size_t)(by * 64 + r) * HS + bx * 64 + tx] = v;
            tile[r][tx] = v;
        }
        __syncthreads();
#pragma unroll
        for (int rr = 0; rr < 64; rr += 4)
            W2T[(size_t)(bx * 64 + ty + rr) * HS + by * 64 + tx] = tile[tx][ty + rr];
    } else {
        const int idx = (b - 8448) * 256 + threadIdx.x;   // 0..73727
        out[idx] = (idx < NXS) ? b3[0] : 0.f;
    }
}

// -------- GEMM: 128x128 tile, 8 waves (512 thr), BK=64, swizzled LDS --------
// MODE 0: C = Z1 @ W2c^T; epilogue: tanh -> V (bf16), y += z2*W3 atomics -> yOut
// MODE 1: C = U = V @ W2 (B=W2T); fused MFMA epilogue:
//         c = U*(1-z1^2) -> LDS -> D[128x8] = c @ W1slice via 4 MFMAs/wave
//         -> atomics into dOut[k*NXS+row]. No U materialization.
template <int MODE>
__global__ __launch_bounds__(512, 4) void gemm_k(
    const uint16_t* __restrict__ A, const uint16_t* __restrict__ B,
    const float* __restrict__ bias, const float* __restrict__ W3,
    uint16_t* __restrict__ Out, float* __restrict__ yOut,
    const uint16_t* __restrict__ Z1, const float* __restrict__ W1,
    float* __restrict__ dOut)
{
    // 64 KB: lsA[2] = u16 [0,16384), lsB[2] = u16 [16384,32768)
    __shared__ __attribute__((aligned(16))) uint16_t smem[32768];
    const int t = threadIdx.x;
    const int wave = t >> 6, lane = t & 63;
    const int lq = lane >> 4, lr = lane & 15;
    const int wm = wave >> 1, wn = wave & 1;         // wm 0..3, wn 0..1
    const int rowBase = blockIdx.x * 128;
    const int colBase = blockIdx.y * 128;

    const int s0 = t, s1 = 512 + t;
    const int r0 = s0 >> 3, q0 = (s0 & 7) ^ (r0 & 7);
    const int r1 = s1 >> 3, q1 = (s1 & 7) ^ (r1 & 7);
    const uint16_t* gA0 = A + (size_t)(rowBase + r0) * HS + q0 * 8;
    const uint16_t* gA1 = A + (size_t)(rowBase + r1) * HS + q1 * 8;
    const uint16_t* gB0 = B + (size_t)(colBase + r0) * HS + q0 * 8;
    const uint16_t* gB1 = B + (size_t)(colBase + r1) * HS + q1 * 8;

    f32x4 acc[2][4] = {};

    async_cp16(gA0, (char*)smem + s0 * 16);
    async_cp16(gA1, (char*)smem + s1 * 16);
    async_cp16(gB0, (char*)smem + 32768 + s0 * 16);
    async_cp16(gB1, (char*)smem + 32768 + s1 * 16);
    __syncthreads();

    int buf = 0;
    for (int k0 = 0; k0 < HS; k0 += 64, buf ^= 1) {
        if (k0 + 64 < HS) {
            const int ko = k0 + 64;
            const int bo = (buf ^ 1) * 16384;
            async_cp16(gA0 + ko, (char*)smem + bo + s0 * 16);
            async_cp16(gA1 + ko, (char*)smem + bo + s1 * 16);
            async_cp16(gB0 + ko, (char*)smem + 32768 + bo + s0 * 16);
            async_cp16(gB1 + ko, (char*)smem + 32768 + bo + s1 * 16);
        }
        const short* pA = (const short*)smem + buf * 8192;
        const short* pB = (const short*)smem + 16384 + buf * 8192;
#pragma unroll
        for (int kk = 0; kk < 64; kk += 32) {
            const int kq = (kk >> 3) + lq;
            short8 af[2], bfr[4];
#pragma unroll
            for (int ti = 0; ti < 2; ++ti) {
                int ar = wm * 32 + ti * 16 + lr;
                af[ti] = *(const short8*)(pA + ar * 64 + ((kq ^ (ar & 7)) << 3));
            }
#pragma unroll
            for (int tj = 0; tj < 4; ++tj) {
                int br = wn * 64 + tj * 16 + lr;
                bfr[tj] = *(const short8*)(pB + br * 64 + ((kq ^ (br & 7)) << 3));
            }
#pragma unroll
            for (int ti = 0; ti < 2; ++ti)
#pragma unroll
                for (int tj = 0; tj < 4; ++tj)
                    acc[ti][tj] = __builtin_amdgcn_mfma_f32_16x16x32_bf16(
                        af[ti], bfr[tj], acc[ti][tj], 0, 0, 0);
        }
        __syncthreads();
    }

    if (MODE == 0) {
        float cB[4], cW[4]; int cCol[4];
#pragma unroll
        for (int tj = 0; tj < 4; ++tj) {
            cCol[tj] = colBase + wn * 64 + tj * 16 + lr;
            cB[tj] = bias[cCol[tj]];
            cW[tj] = W3[cCol[tj]];
        }
#pragma unroll
        for (int ti = 0; ti < 2; ++ti) {
#pragma unroll
            for (int r = 0; r < 4; ++r) {
                int row = rowBase + wm * 32 + ti * 16 + lq * 4 + r;
                float ys = 0.f;
#pragma unroll
                for (int tj = 0; tj < 4; ++tj) {
                    float z2 = tanhf(acc[ti][tj][r] + cB[tj]);
                    ys += z2 * cW[tj];
                    Out[(size_t)row * HS + cCol[tj]] = f2bf((1.f - z2 * z2) * cW[tj]);
                }
                ys += __shfl_xor(ys, 1); ys += __shfl_xor(ys, 2);
                ys += __shfl_xor(ys, 4); ys += __shfl_xor(ys, 8);
                if (lr == 0) atomicAdd(&yOut[row], ys);
            }
        }
    } else {
        // c = U*(1-z1^2) -> LDS (row-major, stride 136 u16 = 272 B, 16B-aligned)
#pragma unroll
        for (int ti = 0; ti < 2; ++ti)
#pragma unroll
            for (int r = 0; r < 4; ++r) {
                int rowl = wm * 32 + ti * 16 + lq * 4 + r;
                const size_t zrow = (size_t)(rowBase + rowl) * HS + colBase;
#pragma unroll
                for (int tj = 0; tj < 4; ++tj) {
                    int coll = wn * 64 + tj * 16 + lr;
                    float z1 = bf2f(Z1[zrow + coll]);
                    smem[rowl * 136 + coll] =
                        f2bf(acc[ti][tj][r] * (1.f - z1 * z1));
                }
            }
        __syncthreads();
        // W1 B-fragment: w1f[kb] holds B[n=lr][k=lq*8+j] = W1[col][lr] (lr<8)
        short8 w1f[4];
#pragma unroll
        for (int kb = 0; kb < 4; ++kb) {
            short8 v;
#pragma unroll
            for (int j = 0; j < 8; ++j) {
                float w = (lr < 8)
                    ? W1[(size_t)(colBase + kb * 32 + lq * 8 + j) * 8 + lr] : 0.f;
                ((short*)&v)[j] = (short)f2bf(w);
            }
            w1f[kb] = v;
        }
        f32x4 dd = {};
#pragma unroll
        for (int kb = 0; kb < 4; ++kb) {
            short8 aF = *(const short8*)(smem + (wave * 16 + lr) * 136
                                         + kb * 32 + lq * 8);
            dd = __builtin_amdgcn_mfma_f32_16x16x32_bf16(aF, w1f[kb], dd, 0, 0, 0);
        }
        if (lr < 8) {
            int row = rowBase + wave * 16 + lq * 4;
#pragma unroll
            for (int rg = 0; rg < 4; ++rg)
                atomicAdd(&dOut[(size_t)lr * NXS + row + rg], dd[rg]);
        }
    }
}

extern "C" void kernel_launch(void* const* d_in, const int* in_sizes, int n_in,
                              void* d_out, int out_size, void* d_ws, size_t ws_size,
                              hipStream_t stream) {
    (void)in_sizes; (void)n_in; (void)out_size; (void)ws_size;
    const float* x  = (const float*)d_in[0];
    const float* W1 = (const float*)d_in[1];
    const float* b1 = (const float*)d_in[2];
    const float* W2 = (const float*)d_in[3];
    const float* b2 = (const float*)d_in[4];
    const float* W3 = (const float*)d_in[5];
    const float* b3 = (const float*)d_in[6];
    float* out = (float*)d_out;

    char* ws = (char*)d_ws;
    // ws layout:
    //   [0, 16MB)    Z1 bf16 (live through GEMM2's epilogue)
    //   [16MB, 32MB) V bf16
    //   [32MB, 34MB) W2c bf16 row-major
    //   [34MB, 36MB) W2T bf16 transposed
    uint16_t* Z1  = (uint16_t*)(ws);
    uint16_t* V   = (uint16_t*)(ws + (size_t)16 * 1024 * 1024);
    uint16_t* W2c = (uint16_t*)(ws + (size_t)32 * 1024 * 1024);
    uint16_t* W2T = (uint16_t*)(ws + (size_t)34 * 1024 * 1024);

    k01<<<8736, 256, 0, stream>>>(x, W1, b1, W2, b3, Z1, W2c, W2T, out);
    gemm_k<0><<<dim3(NXS / 128, HS / 128), 512, 0, stream>>>(
        Z1, W2c, b2, W3, V, out, nullptr, nullptr, nullptr);
    gemm_k<1><<<dim3(NXS / 128, HS / 128), 512, 0, stream>>>(
        V, W2T, nullptr, nullptr, nullptr, nullptr, Z1, W1, out + NXS);
}

// Round 8
// 147.233 us; speedup vs baseline: 1.1247x; 1.0296x over previous
//
#include <hip/hip_runtime.h>
#include <stdint.h>

#define NXS 8192
#define HS  1024

typedef __attribute__((ext_vector_type(8))) short short8;
typedef __attribute__((ext_vector_type(4))) float f32x4;

__device__ __forceinline__ float bf2f(uint32_t b) {
    union { uint32_t u; float f; } c; c.u = b << 16; return c.f;
}
__device__ __forceinline__ uint16_t f2bf(float f) {
    union { float f; uint32_t u; } c; c.f = f;
    return (uint16_t)((c.u + 0x7fffu + ((c.u >> 16) & 1u)) >> 16);
}
__device__ __forceinline__ void async_cp16(const void* g, void* l) {
    __builtin_amdgcn_global_load_lds(
        (const __attribute__((address_space(1))) void*)g,
        (__attribute__((address_space(3))) void*)l,
        16, 0, 0);
}

// ---- K01: merged prep ----
// blocks [0,1024):      Z1 = tanh(x@W1^T+b1), 8 samples/block, W1 in registers
// blocks [1024,1280):   W2 fp32 -> W2c (bf16) + W2T (bf16 transposed)
// blocks [1280,1568):   init out: y = b3, dydx = 0
// blocks [1568,1632):   W1T[16][1024] bf16: rows 0-7 = W1^T, rows 8-15 = 0
__global__ __launch_bounds__(256) void k01(
    const float* __restrict__ x, const float* __restrict__ W1,
    const float* __restrict__ b1, const float* __restrict__ W2,
    const float* __restrict__ b3, uint16_t* __restrict__ Z1,
    uint16_t* __restrict__ W2c, uint16_t* __restrict__ W2T,
    uint16_t* __restrict__ W1T, float* __restrict__ out)
{
    __shared__ float xs[8][8];
    __shared__ uint16_t tile[64][65];
    const int b = blockIdx.x;
    const int t = threadIdx.x;
    if (b < 1024) {
        const int n0 = b * 8;
        if (t < 64) xs[t >> 3][t & 7] = x[n0 * 8 + t];
        const int j = t * 4;
        float w[4][8];
#pragma unroll
        for (int c = 0; c < 4; ++c) {
            float4 w0 = *(const float4*)(W1 + (j + c) * 8);
            float4 w1 = *(const float4*)(W1 + (j + c) * 8 + 4);
            w[c][0] = w0.x; w[c][1] = w0.y; w[c][2] = w0.z; w[c][3] = w0.w;
            w[c][4] = w1.x; w[c][5] = w1.y; w[c][6] = w1.z; w[c][7] = w1.w;
        }
        float4 bb = *(const float4*)(b1 + j);
        const float bv[4] = {bb.x, bb.y, bb.z, bb.w};
        __syncthreads();
#pragma unroll
        for (int s = 0; s < 8; ++s) {
            ushort4 o;
            uint16_t* op = (uint16_t*)&o;
#pragma unroll
            for (int c = 0; c < 4; ++c) {
                float sum = bv[c];
#pragma unroll
                for (int k = 0; k < 8; ++k) sum += xs[s][k] * w[c][k];
                op[c] = f2bf(tanhf(sum));
            }
            *(ushort4*)(Z1 + (size_t)(n0 + s) * HS + j) = o;
        }
    } else if (b < 1280) {
        const int bb2 = b - 1024;
        const int bx = bb2 & 15, by = bb2 >> 4;
        const int tx = t & 63, ty = t >> 6;
#pragma unroll
        for (int rr = 0; rr < 64; rr += 4) {
            int r = ty + rr;
            uint16_t v = f2bf(W2[(size_t)(by * 64 + r) * HS + bx * 64 + tx]);
            W2c[(size_t)(by * 64 + r) * HS + bx * 64 + tx] = v;
            tile[r][tx] = v;
        }
        __syncthreads();
#pragma unroll
        for (int rr = 0; rr < 64; rr += 4)
            W2T[(size_t)(bx * 64 + ty + rr) * HS + by * 64 + tx] = tile[tx][ty + rr];
    } else if (b < 1568) {
        const int idx = (b - 1280) * 256 + t;   // 0..73727
        out[idx] = (idx < NXS) ? b3[0] : 0.f;
    } else {
        const int idx = (b - 1568) * 256 + t;   // 0..16383
        const int r = idx >> 10, c = idx & 1023;
        W1T[idx] = (r < 8) ? f2bf(W1[c * 8 + r]) : (uint16_t)0;
    }
}

// -------- GEMM: 64x128 tile, 4 waves (256 thr), BK=32, dbuf, swizzled LDS ----
// MODE 0: C = Z1 @ W2c^T; epilogue: tanh -> V (bf16), y += z2*W3 atomics
// MODE 1: C = U = V @ W2 (B=W2T); fused MFMA epilogue:
//         c = U*(1-z1^2) -> LDS -> D[64x8] = c @ W1T-slice via 4 MFMAs/wave
//         -> fp32 atomics into dOut[k*NXS+row]
template <int MODE>
__global__ __launch_bounds__(256, 4) void gemm_k(
    const uint16_t* __restrict__ A, const uint16_t* __restrict__ B,
    const float* __restrict__ bias, const float* __restrict__ W3,
    uint16_t* __restrict__ Out, float* __restrict__ yOut,
    const uint16_t* __restrict__ Z1, const uint16_t* __restrict__ W1T,
    float* __restrict__ dOut)
{
    // 24 KB u16[12288]: A bufs [0,2048)+[2048,4096); B bufs [4096,8192)+[8192,12288)
    __shared__ __attribute__((aligned(16))) uint16_t smem[12288];
    const int t = threadIdx.x;
    const int wave = t >> 6, lane = t & 63;
    const int lq = lane >> 4, lr = lane & 15;
    const int wm = wave >> 1, wn = wave & 1;   // wm 0..1 (32 rows), wn 0..1 (64 cols)
    const int rowBase = blockIdx.x * 64;
    const int colBase = blockIdx.y * 128;

    // A: 256 segs (64 rows x 4 slots); B: 512 segs (128 rows x 4 slots)
    const int rA = t >> 2, qA = (t & 3) ^ (rA & 3);
    const int sB0 = t, sB1 = 256 + t;
    const int rB0 = sB0 >> 2, qB0 = (sB0 & 3) ^ (rB0 & 3);
    const int rB1 = sB1 >> 2, qB1 = (sB1 & 3) ^ (rB1 & 3);
    const uint16_t* gA  = A + (size_t)(rowBase + rA) * HS + qA * 8;
    const uint16_t* gB0 = B + (size_t)(colBase + rB0) * HS + qB0 * 8;
    const uint16_t* gB1 = B + (size_t)(colBase + rB1) * HS + qB1 * 8;

    f32x4 acc[2][4] = {};

    async_cp16(gA,  (char*)smem + t * 16);
    async_cp16(gB0, (char*)smem + 8192 + sB0 * 16);
    async_cp16(gB1, (char*)smem + 8192 + sB1 * 16);
    __syncthreads();

    int buf = 0;
    for (int k0 = 0; k0 < HS; k0 += 32, buf ^= 1) {
        if (k0 + 32 < HS) {
            const int ko = k0 + 32;
            async_cp16(gA + ko,  (char*)smem + (buf ^ 1) * 4096 + t * 16);
            async_cp16(gB0 + ko, (char*)smem + 8192 + (buf ^ 1) * 8192 + sB0 * 16);
            async_cp16(gB1 + ko, (char*)smem + 8192 + (buf ^ 1) * 8192 + sB1 * 16);
        }
        const short* pA = (const short*)smem + buf * 2048;
        const short* pB = (const short*)smem + 4096 + buf * 4096;
        short8 af[2], bfr[4];
#pragma unroll
        for (int ti = 0; ti < 2; ++ti) {
            int ar = wm * 32 + ti * 16 + lr;
            af[ti] = *(const short8*)(pA + ar * 32 + ((lq ^ (ar & 3)) << 3));
        }
#pragma unroll
        for (int tj = 0; tj < 4; ++tj) {
            int br = wn * 64 + tj * 16 + lr;
            bfr[tj] = *(const short8*)(pB + br * 32 + ((lq ^ (br & 3)) << 3));
        }
#pragma unroll
        for (int ti = 0; ti < 2; ++ti)
#pragma unroll
            for (int tj = 0; tj < 4; ++tj)
                acc[ti][tj] = __builtin_amdgcn_mfma_f32_16x16x32_bf16(
                    af[ti], bfr[tj], acc[ti][tj], 0, 0, 0);
        __syncthreads();
    }

    if (MODE == 0) {
        float cB[4], cW[4]; int cCol[4];
#pragma unroll
        for (int tj = 0; tj < 4; ++tj) {
            cCol[tj] = colBase + wn * 64 + tj * 16 + lr;
            cB[tj] = bias[cCol[tj]];
            cW[tj] = W3[cCol[tj]];
        }
#pragma unroll
        for (int ti = 0; ti < 2; ++ti) {
#pragma unroll
            for (int r = 0; r < 4; ++r) {
                int row = rowBase + wm * 32 + ti * 16 + lq * 4 + r;
                float ys = 0.f;
#pragma unroll
                for (int tj = 0; tj < 4; ++tj) {
                    float z2 = tanhf(acc[ti][tj][r] + cB[tj]);
                    ys += z2 * cW[tj];
                    Out[(size_t)row * HS + cCol[tj]] = f2bf((1.f - z2 * z2) * cW[tj]);
                }
                ys += __shfl_xor(ys, 1); ys += __shfl_xor(ys, 2);
                ys += __shfl_xor(ys, 4); ys += __shfl_xor(ys, 8);
                if (lr == 0) atomicAdd(&yOut[row], ys);
            }
        }
    } else {
        // c = U*(1-z1^2) -> LDS rows [64][stride 136 u16]
#pragma unroll
        for (int ti = 0; ti < 2; ++ti)
#pragma unroll
            for (int r = 0; r < 4; ++r) {
                int rowl = wm * 32 + ti * 16 + lq * 4 + r;
                const size_t zrow = (size_t)(rowBase + rowl) * HS + colBase;
#pragma unroll
                for (int tj = 0; tj < 4; ++tj) {
                    int coll = wn * 64 + tj * 16 + lr;
                    float z1 = bf2f(Z1[zrow + coll]);
                    smem[rowl * 136 + coll] =
                        f2bf(acc[ti][tj][r] * (1.f - z1 * z1));
                }
            }
        __syncthreads();
        // D[16x8 per wave] = c-rows [wave*16, +16) @ W1T-slice
        f32x4 dd = {};
#pragma unroll
        for (int kb = 0; kb < 4; ++kb) {
            short8 aF = *(const short8*)(smem + (wave * 16 + lr) * 136
                                         + kb * 32 + lq * 8);
            short8 bF = *(const short8*)(W1T + lr * HS + colBase
                                         + kb * 32 + lq * 8);
            dd = __builtin_amdgcn_mfma_f32_16x16x32_bf16(aF, bF, dd, 0, 0, 0);
        }
        if (lr < 8) {
            int row = rowBase + wave * 16 + lq * 4;
#pragma unroll
            for (int rg = 0; rg < 4; ++rg)
                atomicAdd(&dOut[(size_t)lr * NXS + row + rg], dd[rg]);
        }
    }
}

extern "C" void kernel_launch(void* const* d_in, const int* in_sizes, int n_in,
                              void* d_out, int out_size, void* d_ws, size_t ws_size,
                              hipStream_t stream) {
    (void)in_sizes; (void)n_in; (void)out_size; (void)ws_size;
    const float* x  = (const float*)d_in[0];
    const float* W1 = (const float*)d_in[1];
    const float* b1 = (const float*)d_in[2];
    const float* W2 = (const float*)d_in[3];
    const float* b2 = (const float*)d_in[4];
    const float* W3 = (const float*)d_in[5];
    const float* b3 = (const float*)d_in[6];
    float* out = (float*)d_out;

    char* ws = (char*)d_ws;
    // ws layout:
    //   [0, 16MB)        Z1 bf16 (live through GEMM2's epilogue)
    //   [16MB, 32MB)     V bf16
    //   [32MB, 34MB)     W2c bf16 row-major
    //   [34MB, 36MB)     W2T bf16 transposed
    //   [36MB, +32KB)    W1T bf16 [16][1024] (rows 8..15 zero)
    uint16_t* Z1  = (uint16_t*)(ws);
    uint16_t* V   = (uint16_t*)(ws + (size_t)16 * 1024 * 1024);
    uint16_t* W2c = (uint16_t*)(ws + (size_t)32 * 1024 * 1024);
    uint16_t* W2T = (uint16_t*)(ws + (size_t)34 * 1024 * 1024);
    uint16_t* W1T = (uint16_t*)(ws + (size_t)36 * 1024 * 1024);

    k01<<<1632, 256, 0, stream>>>(x, W1, b1, W2, b3, Z1, W2c, W2T, W1T, out);
    gemm_k<0><<<dim3(NXS / 64, HS / 128), 256, 0, stream>>>(
        Z1, W2c, b2, W3, V, out, nullptr, nullptr, nullptr);
    gemm_k<1><<<dim3(NXS / 64, HS / 128), 256, 0, stream>>>(
        V, W2T, nullptr, nullptr, nullptr, nullptr, Z1, W1T, out + NXS);
}

// Round 9
// 136.777 us; speedup vs baseline: 1.2106x; 1.0764x over previous
//
#include <hip/hip_runtime.h>
#include <stdint.h>

#define NXS 8192
#define HS  1024

typedef __attribute__((ext_vector_type(8))) short short8;
typedef __attribute__((ext_vector_type(4))) float f32x4;

__device__ __forceinline__ float bf2f(uint32_t b) {
    union { uint32_t u; float f; } c; c.u = b << 16; return c.f;
}
__device__ __forceinline__ uint16_t f2bf(float f) {
    union { float f; uint32_t u; } c; c.f = f;
    return (uint16_t)((c.u + 0x7fffu + ((c.u >> 16) & 1u)) >> 16);
}
__device__ __forceinline__ void async_cp16(const void* g, void* l) {
    __builtin_amdgcn_global_load_lds(
        (const __attribute__((address_space(1))) void*)g,
        (__attribute__((address_space(3))) void*)l,
        16, 0, 0);
}

// ---- K01: merged prep ----
// [0,1024):     Z1 = tanh(x@W1^T+b1), 8 samples/block
// [1024,1536):  pack Bp1[g][c][lane][8] = bf16 W2[g*16+lr][c*32+lq*8+j]
// [1536,2048):  pack Bp2[g][c][lane][8] = bf16 W2[c*32+lq*8+j][g*16+lr]
// [2048,2336):  init out: y = b3, dydx = 0
// [2336,2400):  W1T[16][1024] bf16 (rows 8..15 zero)
__global__ __launch_bounds__(256) void k01(
    const float* __restrict__ x, const float* __restrict__ W1,
    const float* __restrict__ b1, const float* __restrict__ W2,
    const float* __restrict__ b3, uint16_t* __restrict__ Z1,
    uint16_t* __restrict__ Bp1, uint16_t* __restrict__ Bp2,
    uint16_t* __restrict__ W1T, float* __restrict__ out)
{
    __shared__ float xs[8][8];
    const int b = blockIdx.x, t = threadIdx.x;
    if (b < 1024) {
        const int n0 = b * 8;
        if (t < 64) xs[t >> 3][t & 7] = x[n0 * 8 + t];
        const int j = t * 4;
        float w[4][8];
#pragma unroll
        for (int c = 0; c < 4; ++c) {
            float4 w0 = *(const float4*)(W1 + (j + c) * 8);
            float4 w1 = *(const float4*)(W1 + (j + c) * 8 + 4);
            w[c][0] = w0.x; w[c][1] = w0.y; w[c][2] = w0.z; w[c][3] = w0.w;
            w[c][4] = w1.x; w[c][5] = w1.y; w[c][6] = w1.z; w[c][7] = w1.w;
        }
        float4 bb = *(const float4*)(b1 + j);
        const float bv[4] = {bb.x, bb.y, bb.z, bb.w};
        __syncthreads();
#pragma unroll
        for (int s = 0; s < 8; ++s) {
            ushort4 o;
            uint16_t* op = (uint16_t*)&o;
#pragma unroll
            for (int c = 0; c < 4; ++c) {
                float sum = bv[c];
#pragma unroll
                for (int k = 0; k < 8; ++k) sum += xs[s][k] * w[c][k];
                op[c] = f2bf(tanhf(sum));
            }
            *(ushort4*)(Z1 + (size_t)(n0 + s) * HS + j) = o;
        }
    } else if (b < 1536) {
        const int tid = (b - 1024) * 256 + t;            // 0..131071
        const int l = tid & 63, c = (tid >> 6) & 31, g = tid >> 11;
        const int lr = l & 15, lq = l >> 4;
        const float* src = W2 + (size_t)(g * 16 + lr) * HS + c * 32 + lq * 8;
        float4 a0 = *(const float4*)src;
        float4 a1 = *(const float4*)(src + 4);
        uint16_t o[8];
        o[0] = f2bf(a0.x); o[1] = f2bf(a0.y); o[2] = f2bf(a0.z); o[3] = f2bf(a0.w);
        o[4] = f2bf(a1.x); o[5] = f2bf(a1.y); o[6] = f2bf(a1.z); o[7] = f2bf(a1.w);
        *(ushort4*)(Bp1 + (size_t)tid * 8)     = *(ushort4*)&o[0];
        *(ushort4*)(Bp1 + (size_t)tid * 8 + 4) = *(ushort4*)&o[4];
    } else if (b < 2048) {
        const int tid = (b - 1536) * 256 + t;
        const int l = tid & 63, c = (tid >> 6) & 31, g = tid >> 11;
        const int lr = l & 15, lq = l >> 4;
        uint16_t o[8];
#pragma unroll
        for (int j2 = 0; j2 < 8; ++j2)
            o[j2] = f2bf(W2[(size_t)(c * 32 + lq * 8 + j2) * HS + g * 16 + lr]);
        *(ushort4*)(Bp2 + (size_t)tid * 8)     = *(ushort4*)&o[0];
        *(ushort4*)(Bp2 + (size_t)tid * 8 + 4) = *(ushort4*)&o[4];
    } else if (b < 2336) {
        const int idx = (b - 2048) * 256 + t;            // 0..73727
        out[idx] = (idx < NXS) ? b3[0] : 0.f;
    } else {
        const int idx = (b - 2336) * 256 + t;            // 0..16383
        const int r = idx >> 10, cc = idx & 1023;
        W1T[idx] = (r < 8) ? f2bf(W1[cc * 8 + r]) : (uint16_t)0;
    }
}

// -------- GEMM: 64x128 tile, 4 waves, BK=32, A via LDS dbuf, B direct-VGPR ----
// Wave w owns rows[0,64) x cols[w*32, w*32+32): acc[4][2], B-frags wave-unique.
// MODE 0: C = Z1 @ W2^T (Bp1); epilogue: tanh -> V (bf16), y atomics
// MODE 1: C = U = V @ W2 (Bp2); fused MFMA dydx epilogue via W1T
template <int MODE>
__global__ __launch_bounds__(256, 4) void gemm_k(
    const uint16_t* __restrict__ A, const uint16_t* __restrict__ Bp,
    const float* __restrict__ bias, const float* __restrict__ W3,
    uint16_t* __restrict__ Out, float* __restrict__ yOut,
    const uint16_t* __restrict__ Z1, const uint16_t* __restrict__ W1T,
    float* __restrict__ dOut)
{
    // 24 KB: A dbuf 2 x 2048 u16 at [0,4096); epilogue c-matrix reuses [0,8704)
    __shared__ __attribute__((aligned(16))) uint16_t smem[12288];
    const int t = threadIdx.x;
    const int wave = t >> 6, lane = t & 63;
    const int lq = lane >> 4, lr = lane & 15;
    const int rowBase = blockIdx.x * 64;
    const int colBase = blockIdx.y * 128;

    // A staging: 256 segs (64 rows x 4 slots), 1 per thread, xor-swizzled
    const int rA = t >> 2, qA = (t & 3) ^ (rA & 3);
    const uint16_t* gA = A + (size_t)(rowBase + rA) * HS + qA * 8;

    // B fragment stream: g0 = colBase/16 + wave*2; frag(g,c) at ((g*32+c)*64+lane)*8
    const uint16_t* pB0 = Bp + ((size_t)(colBase >> 4) + wave * 2) * 16384 + (size_t)lane * 8;
    const uint16_t* pB1 = pB0 + 16384;

    f32x4 acc[4][2] = {};

    async_cp16(gA, (char*)smem + t * 16);
    short8 b0 = *(const short8*)pB0;
    short8 b1 = *(const short8*)pB1;
    __syncthreads();

    int buf = 0;
    for (int c = 0; c < 32; ++c, buf ^= 1) {
        short8 b0n = b0, b1n = b1;
        if (c < 31) {
            async_cp16(gA + (c + 1) * 32, (char*)smem + (buf ^ 1) * 4096 + t * 16);
            b0n = *(const short8*)(pB0 + (c + 1) * 512);
            b1n = *(const short8*)(pB1 + (c + 1) * 512);
        }
        const short* pA = (const short*)smem + buf * 2048;
        short8 af[4];
#pragma unroll
        for (int ti = 0; ti < 4; ++ti) {
            int ar = ti * 16 + lr;
            af[ti] = *(const short8*)(pA + ar * 32 + ((lq ^ (ar & 3)) << 3));
        }
#pragma unroll
        for (int ti = 0; ti < 4; ++ti) {
            acc[ti][0] = __builtin_amdgcn_mfma_f32_16x16x32_bf16(af[ti], b0, acc[ti][0], 0, 0, 0);
            acc[ti][1] = __builtin_amdgcn_mfma_f32_16x16x32_bf16(af[ti], b1, acc[ti][1], 0, 0, 0);
        }
        __syncthreads();
        b0 = b0n; b1 = b1n;
    }

    if (MODE == 0) {
        float cB[2], cW[2]; int cCol[2];
#pragma unroll
        for (int tj = 0; tj < 2; ++tj) {
            cCol[tj] = colBase + wave * 32 + tj * 16 + lr;
            cB[tj] = bias[cCol[tj]];
            cW[tj] = W3[cCol[tj]];
        }
#pragma unroll
        for (int ti = 0; ti < 4; ++ti) {
#pragma unroll
            for (int r = 0; r < 4; ++r) {
                int row = rowBase + ti * 16 + lq * 4 + r;
                float ys = 0.f;
#pragma unroll
                for (int tj = 0; tj < 2; ++tj) {
                    float z2 = tanhf(acc[ti][tj][r] + cB[tj]);
                    ys += z2 * cW[tj];
                    Out[(size_t)row * HS + cCol[tj]] = f2bf((1.f - z2 * z2) * cW[tj]);
                }
                ys += __shfl_xor(ys, 1); ys += __shfl_xor(ys, 2);
                ys += __shfl_xor(ys, 4); ys += __shfl_xor(ys, 8);
                if (lr == 0) atomicAdd(&yOut[row], ys);
            }
        }
    } else {
        // c = U*(1-z1^2) -> LDS rows [64][stride 136 u16]
#pragma unroll
        for (int ti = 0; ti < 4; ++ti)
#pragma unroll
            for (int r = 0; r < 4; ++r) {
                int rowl = ti * 16 + lq * 4 + r;
                const size_t zrow = (size_t)(rowBase + rowl) * HS + colBase;
#pragma unroll
                for (int tj = 0; tj < 2; ++tj) {
                    int coll = wave * 32 + tj * 16 + lr;
                    float z1 = bf2f(Z1[zrow + coll]);
                    smem[rowl * 136 + coll] =
                        f2bf(acc[ti][tj][r] * (1.f - z1 * z1));
                }
            }
        __syncthreads();
        // D[16x8 per wave] = c-rows [wave*16,+16) @ W1T-slice, via 4 MFMAs
        f32x4 dd = {};
#pragma unroll
        for (int kb = 0; kb < 4; ++kb) {
            short8 aF = *(const short8*)(smem + (wave * 16 + lr) * 136
                                         + kb * 32 + lq * 8);
            short8 bF = *(const short8*)(W1T + lr * HS + colBase
                                         + kb * 32 + lq * 8);
            dd = __builtin_amdgcn_mfma_f32_16x16x32_bf16(aF, bF, dd, 0, 0, 0);
        }
        if (lr < 8) {
            int row = rowBase + wave * 16 + lq * 4;
#pragma unroll
            for (int rg = 0; rg < 4; ++rg)
                atomicAdd(&dOut[(size_t)lr * NXS + row + rg], dd[rg]);
        }
    }
}

extern "C" void kernel_launch(void* const* d_in, const int* in_sizes, int n_in,
                              void* d_out, int out_size, void* d_ws, size_t ws_size,
                              hipStream_t stream) {
    (void)in_sizes; (void)n_in; (void)out_size; (void)ws_size;
    const float* x  = (const float*)d_in[0];
    const float* W1 = (const float*)d_in[1];
    const float* b1 = (const float*)d_in[2];
    const float* W2 = (const float*)d_in[3];
    const float* b2 = (const float*)d_in[4];
    const float* W3 = (const float*)d_in[5];
    const float* b3 = (const float*)d_in[6];
    float* out = (float*)d_out;

    char* ws = (char*)d_ws;
    // ws layout:
    //   [0, 16MB)     Z1 bf16 (live through GEMM2's epilogue)
    //   [16MB, 32MB)  V bf16
    //   [32MB, 34MB)  Bp1 bf16 fragment-packed W2   (GEMM1 B)
    //   [34MB, 36MB)  Bp2 bf16 fragment-packed W2^T (GEMM2 B)
    //   [36MB, +32KB) W1T bf16 [16][1024] (rows 8..15 zero)
    uint16_t* Z1  = (uint16_t*)(ws);
    uint16_t* V   = (uint16_t*)(ws + (size_t)16 * 1024 * 1024);
    uint16_t* Bp1 = (uint16_t*)(ws + (size_t)32 * 1024 * 1024);
    uint16_t* Bp2 = (uint16_t*)(ws + (size_t)34 * 1024 * 1024);
    uint16_t* W1T = (uint16_t*)(ws + (size_t)36 * 1024 * 1024);

    k01<<<2400, 256, 0, stream>>>(x, W1, b1, W2, b3, Z1, Bp1, Bp2, W1T, out);
    gemm_k<0><<<dim3(NXS / 64, HS / 128), 256, 0, stream>>>(
        Z1, Bp1, b2, W3, V, out, nullptr, nullptr, nullptr);
    gemm_k<1><<<dim3(NXS / 64, HS / 128), 256, 0, stream>>>(
        V, Bp2, nullptr, nullptr, nullptr, nullptr, Z1, W1T, out + NXS);
}